// Round 1
// baseline (199.766 us; speedup 1.0000x reference)
//
#include <hip/hip_runtime.h>
#include <stdint.h>

// Problem constants (from reference): B=2, S=4096, D_MODEL=1024, H=16, d_k=64
// RADIUS = ceil(sqrt(4*0.28*ln(1e6))*2) = 8, window = 9 (positions s-8..s)
constexpr int S_LEN = 4096;
constexpr int DM    = 1024;
constexpr int RAD   = 8;
constexpr float INV2T = 1.7857142857142858f; // 1/(2*0.28)

typedef _Float16 h8v __attribute__((ext_vector_type(8)));  // 8 f16 (4 VGPRs) MFMA frag
typedef float f32x4  __attribute__((ext_vector_type(4)));  // MFMA accumulator

// async global->LDS, 16B/lane. LDS dst is wave-uniform base + lane*16 (HW rule).
static __device__ __forceinline__ void gl_lds16(const void* gp, void* lp) {
  auto g = (const __attribute__((address_space(1))) void*)(uintptr_t)gp;
  auto l = (__attribute__((address_space(3))) void*)(uint32_t)(uintptr_t)lp;
  __builtin_amdgcn_global_load_lds(g, l, 16, 0, 0);
}

// ---------------- prep: x->fp16 cast + 4x W transpose-cast, one launch -------
__global__ __launch_bounds__(256) void sda_prep_kernel(
    const float* __restrict__ X, _Float16* __restrict__ XH,
    const float* __restrict__ W0, const float* __restrict__ W1,
    const float* __restrict__ W2, const float* __restrict__ W3,
    _Float16* __restrict__ T0, _Float16* __restrict__ T1,
    _Float16* __restrict__ T2, _Float16* __restrict__ T3) {
  __shared__ float t[32][33];
  int z = blockIdx.z;
  int tx = threadIdx.x, ty = threadIdx.y;
  if (z < 4) {
    const float* W = z == 0 ? W0 : (z == 1 ? W1 : (z == 2 ? W2 : W3));
    _Float16*    T = z == 0 ? T0 : (z == 1 ? T1 : (z == 2 ? T2 : T3));
    int n0 = blockIdx.x * 32, k0 = blockIdx.y * 32;
#pragma unroll
    for (int i = 0; i < 4; ++i)
      t[ty + 8 * i][tx] = W[(size_t)(k0 + ty + 8 * i) * DM + n0 + tx];
    __syncthreads();
#pragma unroll
    for (int i = 0; i < 4; ++i)
      T[(size_t)(n0 + ty + 8 * i) * DM + k0 + tx] = (_Float16)t[tx][ty + 8 * i];
  } else {
    int blk = (z - 4) * 1024 + blockIdx.y * 32 + blockIdx.x;
    int i = blk * 256 + ty * 32 + tx;
    const float4* x4 = (const float4*)X;
    float4 a = x4[2 * i], b = x4[2 * i + 1];
    float f[8] = {a.x, a.y, a.z, a.w, b.x, b.y, b.z, b.w};
    union { _Float16 h[8]; uint4 v; } o;
#pragma unroll
    for (int j = 0; j < 8; ++j) o.h[j] = (_Float16)f[j];
    ((uint4*)XH)[i] = o.v;
  }
}

// ---------------- pipelined GEMM (T1+T2+T3-lite+T4+T5) ----------------------
// BM=128, BN=256, BK=64, 512 thr = 8 waves (2 M x 4 N), per-wave 64x64 out.
// Triple-buffered LDS (3 x 48KB = 144KB), 2-tiles-ahead prefetch via
// global_load_lds (6 loads/thread/tile, split 3+3 across the 2 phases).
// Counted s_waitcnt vmcnt(9) -- loads stay in flight ACROSS raw s_barriers
// (never drained to 0 in the main loop). s_setprio(1) around MFMA clusters.
// XOR-chunk LDS swizzle identical to the verified R6 kernel (0 conflicts).
// Accumulation order is bit-identical to the previous 128x128 kernel.
template <bool F32OUT>
__global__ __launch_bounds__(512) void sda_gemm_pipe(
    const _Float16* __restrict__ A, const _Float16* __restrict__ Bt,
    _Float16* __restrict__ C0, _Float16* __restrict__ C1,
    _Float16* __restrict__ C2, float* __restrict__ Cf) {
  constexpr int Kd = DM;
  constexpr int NT = Kd / 64;            // 16 K-tiles
  constexpr int ASZ = 128 * 64;          // f16 elems per A buffer (16 KB)
  constexpr int BSZ = 256 * 64;          // f16 elems per B buffer (32 KB)
  __shared__ __align__(16) _Float16 As[3][ASZ];  // 48 KB
  __shared__ __align__(16) _Float16 Bs[3][BSZ];  // 96 KB  => 144 KB total

  int blk = blockIdx.x;
  int xcd = blk & 7, slot = blk >> 3;
  int xt = slot >> 3, ys = slot & 7;     // x-major within XCD (B-panel reuse)
  int yt = (xcd << 3) | ys;              // y-stripe per XCD (A-panel reuse)
  int m0 = yt * 128, n0 = xt * 256;

  int tid = threadIdx.x, wid = tid >> 6, lane = tid & 63;
  int srow = lane >> 3;                  // staging row within 8-row group
  int sgk = ((lane & 7) ^ srow) * 8;     // XOR-permuted global k-chunk (T2)
  int wm = (wid >> 2) * 64, wn = (wid & 3) * 64;
  int fm = lane & 15, fc = lane >> 4;

  // wave-private global staging bases: wave w stages A rows [16w,16w+16),
  // B rows [32w, 32w+32), 8 rows per gl_lds sweep.
  const _Float16* Ag = A  + (size_t)(m0 + 16 * wid + srow) * Kd + sgk;
  const _Float16* Bg = Bt + (size_t)(n0 + 32 * wid + srow) * Kd + sgk;

  f32x4 acc[4][4] = {};

  // group 1: 3 loads (A sweep0, A sweep1, B sweep0)
  auto stage_g1 = [&](int buf, int kt) {
    int kk = kt * 64;
    gl_lds16(Ag + kk,           &As[buf][(16 * wid) * 64]);
    gl_lds16(Ag + kk + 8 * Kd,  &As[buf][(16 * wid + 8) * 64]);
    gl_lds16(Bg + kk,           &Bs[buf][(32 * wid) * 64]);
  };
  // group 2: 3 loads (B sweeps 1..3)
  auto stage_g2 = [&](int buf, int kt) {
    int kk = kt * 64;
    gl_lds16(Bg + kk + 8 * Kd,  &Bs[buf][(32 * wid + 8) * 64]);
    gl_lds16(Bg + kk + 16 * Kd, &Bs[buf][(32 * wid + 16) * 64]);
    gl_lds16(Bg + kk + 24 * Kd, &Bs[buf][(32 * wid + 24) * 64]);
  };

  // one phase = read frags for one K=32 slice + 16 MFMAs
  auto phase = [&](int buf, int kk) {
    h8v a[4], b[4];
#pragma unroll
    for (int i = 0; i < 4; ++i) {
      int row = wm + i * 16 + fm;
      a[i] = *(const h8v*)&As[buf][row * 64 + (((kk * 4 + fc) ^ (row & 7)) * 8)];
    }
#pragma unroll
    for (int j = 0; j < 4; ++j) {
      int row = wn + j * 16 + fm;
      b[j] = *(const h8v*)&Bs[buf][row * 64 + (((kk * 4 + fc) ^ (row & 7)) * 8)];
    }
    __builtin_amdgcn_s_setprio(1);
#pragma unroll
    for (int i = 0; i < 4; ++i)
#pragma unroll
      for (int j = 0; j < 4; ++j)
        acc[i][j] = __builtin_amdgcn_mfma_f32_16x16x32_f16(a[i], b[j], acc[i][j], 0, 0, 0);
    __builtin_amdgcn_s_setprio(0);
  };

  // prologue: tiles 0 and 1 fully in flight (12 loads/thread outstanding)
  stage_g1(0, 0); stage_g2(0, 0);
  stage_g1(1, 1); stage_g2(1, 1);

  int cur = 0;
#pragma unroll 1
  for (int t = 0; t < NT; ++t) {
    int nb = cur + 2; if (nb >= 3) nb -= 3;   // buffer for tile t+2
    // ---- phase A ----
    if (t + 2 < NT) {
      stage_g1(nb, t + 2);
      // tile t's 6 loads done; t+1's 6 + t+2's first 3 stay in flight
      asm volatile("s_waitcnt vmcnt(9)" ::: "memory");
    } else if (t + 1 < NT) {
      asm volatile("s_waitcnt vmcnt(6)" ::: "memory");
    } else {
      asm volatile("s_waitcnt vmcnt(0)" ::: "memory");
    }
    asm volatile("s_barrier" ::: "memory");   // tile t resident for ALL waves
    phase(cur, 0);
    // ---- phase B ----
    if (t + 2 < NT) stage_g2(nb, t + 2);
    asm volatile("s_barrier" ::: "memory");   // lockstep mid-tile
    phase(cur, 1);
    asm volatile("s_barrier" ::: "memory");   // all waves done reading buf[cur]
                                              // before next iter overwrites it
    cur = cur == 2 ? 0 : cur + 1;
  }

  int rr = (lane >> 4) * 4, cc = lane & 15;
  if constexpr (F32OUT) {
#pragma unroll
    for (int i = 0; i < 4; ++i)
#pragma unroll
      for (int j = 0; j < 4; ++j) {
        size_t base = (size_t)(m0 + wm + i * 16 + rr) * DM + (n0 + wn + j * 16 + cc);
#pragma unroll
        for (int r = 0; r < 4; ++r)
          Cf[base + (size_t)r * DM] = acc[i][j][r];
      }
  } else {
    int which = n0 >> 10, nc = n0 & 1023;    // BN=256 never crosses a 1024 boundary
    _Float16* Cv = which == 0 ? C0 : (which == 1 ? C1 : C2);
#pragma unroll
    for (int i = 0; i < 4; ++i)
#pragma unroll
      for (int j = 0; j < 4; ++j) {
        size_t base = (size_t)(m0 + wm + i * 16 + rr) * DM + (nc + wn + j * 16 + cc);
#pragma unroll
        for (int r = 0; r < 4; ++r)
          Cv[base + (size_t)r * DM] = (_Float16)acc[i][j][r];
      }
  }
}

// ---------------- BARRIER-FREE per-wave windowed attention ----------------
// Grid (S/64, B*H), 256 thr = 4 waves. Wave w owns q-rows [16w,16w+16) and
// needs ONLY K/V pos [s0+16w-8, s0+16w+15] (24 rows) -> per-wave LDS slices,
// ZERO __syncthreads (in-wave DS ordering via lgkmcnt only, per ISA wave-
// reduce pattern). Strides are odd-dword multiples (kw 144B, vt/wt 80B,
// sc 132B) -> <=2-way bank aliasing (free, m136); kills the 128B-stride
// 16-way b128 collisions present in R4-R7.
// QK: 4 MFMAs (2 key-tiles x K=64; kw rows 24-31 garbage -> only unused
// score cols). PV: 4 MFMAs (single K=32 covers the zero-padded band; vt
// cols 24-31 zeroed to avoid 0*NaN).
__global__ __launch_bounds__(256) void sda_attn_kernel(
    const _Float16* __restrict__ Q, const _Float16* __restrict__ K,
    const _Float16* __restrict__ V, _Float16* __restrict__ O) {
  constexpr int KS  = 72;  // kw row stride f16: 144B = 36 dw
  constexpr int VTS = 40;  // vt row stride f16: 80B = 20 dw
  constexpr int WS  = 40;  // wt row stride f16
  __shared__ __align__(16) _Float16 kw[4][32 * KS];   // 4.5 KB/wave
  __shared__ __align__(16) _Float16 vt[4][64 * VTS];  // 5 KB/wave [dim][key]
  __shared__ __align__(16) float    sc[4][16 * 33];   // 2.06 KB/wave
  __shared__ __align__(16) _Float16 wt[4][16 * WS];   // 1.25 KB/wave => 52.5 KB total

  int bh = blockIdx.y, b = bh >> 4, h = bh & 15;
  int s0 = blockIdx.x * 64;
  int tid = threadIdx.x, wid = tid >> 6, lane = tid & 63;
  size_t headoff = (size_t)b * S_LEN * DM + h * 64;

  _Float16* kwp = kw[wid];
  _Float16* vtp = vt[wid];
  float*    scp = sc[wid];
  _Float16* wtp = wt[wid];

  int p0 = s0 + wid * 16 - RAD;    // first key pos of this wave's 24-key band
  int fm = lane & 15, fkg = (lane >> 4) * 8;
  int rr = (lane >> 4) * 4, cc = lane & 15;

  // zero wt fully (1280 B = 80 x 16B) and vt key-cols 24..31 (0*NaN guard)
  {
    uint4 z = make_uint4(0, 0, 0, 0);
    ((uint4*)wtp)[lane] = z;
    if (lane < 16) ((uint4*)wtp)[64 + lane] = z;
    *(uint4*)&vtp[lane * VTS + 24] = z;
  }

  // stage K rows 0..23 row-major (24 x 8 chunks = 192 items, 3/lane)
#pragma unroll
  for (int i = 0; i < 3; ++i) {
    int item = i * 64 + lane;
    int row = item >> 3, ch = (item & 7) * 8;
    int pos = p0 + row;
    uint4 kv = make_uint4(0, 0, 0, 0);
    if (pos >= 0) kv = *(const uint4*)(K + headoff + (size_t)pos * DM + ch);
    *(uint4*)&kwp[row * KS + ch] = kv;
  }
  // stage V transposed: vt[dim][key]
#pragma unroll
  for (int i = 0; i < 3; ++i) {
    int item = i * 64 + lane;
    int row = item >> 3, chb = (item & 7) * 8;
    int pos = p0 + row;
    uint4 vv = make_uint4(0, 0, 0, 0);
    if (pos >= 0) vv = *(const uint4*)(V + headoff + (size_t)pos * DM + chb);
    union { uint4 v; _Float16 hh[8]; } u; u.v = vv;
#pragma unroll
    for (int d = 0; d < 8; ++d) vtp[(chb + d) * VTS + row] = u.hh[d];
  }

  // Q fragments straight from global (rows always valid)
  const _Float16* qrow = Q + headoff + (size_t)(s0 + wid * 16 + fm) * DM;
  h8v aq0 = *(const h8v*)(qrow + fkg);
  h8v aq1 = *(const h8v*)(qrow + 32 + fkg);

  // ---- QK^T: 2 local key-tiles x K=64 ----
  f32x4 accs[2] = {};
#pragma unroll
  for (int t = 0; t < 2; ++t) {
    h8v bk0 = *(const h8v*)&kwp[(t * 16 + fm) * KS + fkg];
    h8v bk1 = *(const h8v*)&kwp[(t * 16 + fm) * KS + 32 + fkg];
    accs[t] = __builtin_amdgcn_mfma_f32_16x16x32_f16(aq0, bk0, accs[t], 0, 0, 0);
    accs[t] = __builtin_amdgcn_mfma_f32_16x16x32_f16(aq1, bk1, accs[t], 0, 0, 0);
  }
#pragma unroll
  for (int t = 0; t < 2; ++t)
#pragma unroll
    for (int r = 0; r < 4; ++r)
      scp[(rr + r) * 33 + t * 16 + cc] = accs[t][r];

  // ---- softmax: lane r (0..15) owns q-row r; band cols r..r+8 (< 24) ----
  if (lane < 16) {
    int r = lane, s = s0 + wid * 16 + r;
    const float* my = &scp[r * 33 + r];
    float e[9], mx = -1e30f;
#pragma unroll
    for (int j = 0; j < 9; ++j) {
      float p = my[j] * INV2T;
      e[j] = (s - RAD + j >= 0) ? p : -1e30f;
      mx = fmaxf(mx, e[j]);
    }
    float se = 0.f;
#pragma unroll
    for (int j = 0; j < 9; ++j) { e[j] = __expf(e[j] - mx); se += e[j]; }
    float inv = 1.f / se;
#pragma unroll
    for (int j = 0; j < 9; ++j)
      wtp[r * WS + r + j] = (_Float16)(e[j] * inv);
  }

  // ---- PV: O(16x64) = wt(16x32) @ V(32x64); one K=32 MFMA per n-tile ----
  f32x4 acco[4] = {};
  h8v aw = *(const h8v*)&wtp[fm * WS + fkg];
#pragma unroll
  for (int t = 0; t < 4; ++t) {
    h8v bv = *(const h8v*)&vtp[(t * 16 + fm) * VTS + fkg];
    acco[t] = __builtin_amdgcn_mfma_f32_16x16x32_f16(aw, bv, acco[t], 0, 0, 0);
  }
#pragma unroll
  for (int t = 0; t < 4; ++t)
#pragma unroll
    for (int r = 0; r < 4; ++r)
      O[headoff + (size_t)(s0 + wid * 16 + rr + r) * DM + t * 16 + cc] =
          (_Float16)acco[t][r];
}

extern "C" void kernel_launch(void* const* d_in, const int* in_sizes, int n_in,
                              void* d_out, int out_size, void* d_ws, size_t ws_size,
                              hipStream_t stream) {
  (void)in_sizes; (void)n_in; (void)out_size; (void)ws_size;
  const float* x  = (const float*)d_in[0];
  const float* Wq = (const float*)d_in[1];
  const float* Wk = (const float*)d_in[2];
  const float* Wv = (const float*)d_in[3];
  const float* Wo = (const float*)d_in[4];

  char* ws = (char*)d_ws;
  const size_t MB = 1ull << 20;
  _Float16* xh    = (_Float16*)(ws + 0);        // 16 MB
  _Float16* WqkvT = (_Float16*)(ws + 16 * MB);  // 6 MB: Wq^T|Wk^T|Wv^T
  _Float16* WoT   = (_Float16*)(ws + 22 * MB);  // 2 MB
  _Float16* Qh    = (_Float16*)(ws + 24 * MB);  // 16 MB each
  _Float16* Kh    = (_Float16*)(ws + 40 * MB);
  _Float16* Vh    = (_Float16*)(ws + 56 * MB);
  _Float16* Ah    = (_Float16*)(ws + 72 * MB);  // total 88 MB

  sda_prep_kernel<<<dim3(32, 32, 8), dim3(32, 8), 0, stream>>>(
      x, xh, Wq, Wk, Wv, Wo,
      WqkvT, WqkvT + (size_t)DM * DM, WqkvT + 2ull * DM * DM, WoT);

  // QKV fused: M=8192, N=3072 -> 768 blocks (BM=128 x BN=256), 3 full CU-rounds
  sda_gemm_pipe<false><<<768, 512, 0, stream>>>(xh, WqkvT, Qh, Kh, Vh, nullptr);
  sda_attn_kernel<<<dim3(64, 32), 256, 0, stream>>>(Qh, Kh, Vh, Ah);
  // Wo: M=8192, N=1024 -> 256 blocks, exactly 1 full CU-round
  sda_gemm_pipe<true><<<256, 512, 0, stream>>>(Ah, WoT, nullptr, nullptr, nullptr, (float*)d_out);
}

// Round 3
// 190.299 us; speedup vs baseline: 1.0497x; 1.0497x over previous
//
#include <hip/hip_runtime.h>
#include <stdint.h>

// Problem constants (from reference): B=2, S=4096, D_MODEL=1024, H=16, d_k=64
// RADIUS = ceil(sqrt(4*0.28*ln(1e6))*2) = 8, window = 9 (positions s-8..s)
constexpr int S_LEN = 4096;
constexpr int DM    = 1024;
constexpr int RAD   = 8;
constexpr float INV2T = 1.7857142857142858f; // 1/(2*0.28)

typedef _Float16 h8v __attribute__((ext_vector_type(8)));  // 8 f16 (4 VGPRs) MFMA frag
typedef float f32x4  __attribute__((ext_vector_type(4)));  // MFMA accumulator

// async global->LDS, 16B/lane. LDS dst is wave-uniform base + lane*16 (HW rule).
static __device__ __forceinline__ void gl_lds16(const void* gp, void* lp) {
  auto g = (const __attribute__((address_space(1))) void*)(uintptr_t)gp;
  auto l = (__attribute__((address_space(3))) void*)(uint32_t)(uintptr_t)lp;
  __builtin_amdgcn_global_load_lds(g, l, 16, 0, 0);
}

// ---------------- prep: x->fp16 cast + 4x W transpose-cast, one launch -------
__global__ __launch_bounds__(256) void sda_prep_kernel(
    const float* __restrict__ X, _Float16* __restrict__ XH,
    const float* __restrict__ W0, const float* __restrict__ W1,
    const float* __restrict__ W2, const float* __restrict__ W3,
    _Float16* __restrict__ T0, _Float16* __restrict__ T1,
    _Float16* __restrict__ T2, _Float16* __restrict__ T3) {
  __shared__ float t[32][33];
  int z = blockIdx.z;
  int tx = threadIdx.x, ty = threadIdx.y;
  if (z < 4) {
    const float* W = z == 0 ? W0 : (z == 1 ? W1 : (z == 2 ? W2 : W3));
    _Float16*    T = z == 0 ? T0 : (z == 1 ? T1 : (z == 2 ? T2 : T3));
    int n0 = blockIdx.x * 32, k0 = blockIdx.y * 32;
#pragma unroll
    for (int i = 0; i < 4; ++i)
      t[ty + 8 * i][tx] = W[(size_t)(k0 + ty + 8 * i) * DM + n0 + tx];
    __syncthreads();
#pragma unroll
    for (int i = 0; i < 4; ++i)
      T[(size_t)(n0 + ty + 8 * i) * DM + k0 + tx] = (_Float16)t[tx][ty + 8 * i];
  } else {
    int blk = (z - 4) * 1024 + blockIdx.y * 32 + blockIdx.x;
    int i = blk * 256 + ty * 32 + tx;
    const float4* x4 = (const float4*)X;
    float4 a = x4[2 * i], b = x4[2 * i + 1];
    float f[8] = {a.x, a.y, a.z, a.w, b.x, b.y, b.z, b.w};
    union { _Float16 h[8]; uint4 v; } o;
#pragma unroll
    for (int j = 0; j < 8; ++j) o.h[j] = (_Float16)f[j];
    ((uint4*)XH)[i] = o.v;
  }
}

// ------- QKV GEMM, FAT WAVES: BM=256 x BN=128, 4 waves, per-wave 128x64 ------
// Theory: LDS frag traffic = 0.375 KB/MFMA (vs 0.5 for 64x64 waves) raises the
// LDS-BW MfmaUtil ceiling from ~47-60% to ~62-80%. Keeps R6's stage->sync->
// compute structure and multi-block TLP: 48 KB LDS + <=256 VGPR
// (__launch_bounds__(256,2)) => 2 resident blocks/CU (8 waves) overlap
// staging and MFMA across blocks (m114 mechanism). XOR-chunk swizzle and
// K-accumulation order bit-identical to the verified R6 kernel.
__global__ __launch_bounds__(256, 2) void sda_gemm_qkv_fat(
    const _Float16* __restrict__ A, const _Float16* __restrict__ Bt,
    _Float16* __restrict__ C0, _Float16* __restrict__ C1,
    _Float16* __restrict__ C2) {
  constexpr int Kd = DM;
  constexpr int BM = 256, BN = 128, BK = 64;
  __shared__ __align__(16) _Float16 As[BM * BK];  // 32 KB
  __shared__ __align__(16) _Float16 Bs[BN * BK];  // 16 KB => 48 KB total

  // 768 blocks = 8 XCD x 96 slots; y-minor within XCD: consecutive slots share
  // the B-panel (0.25 MB) and keep 4 A-stripes (2 MB) hot in the XCD L2.
  int blk = blockIdx.x;
  int xcd = blk & 7, slot = blk >> 3;
  int ys = slot & 3, xt = slot >> 2;    // xt in [0,24), ys in [0,4)
  int yt = (xcd << 2) | ys;             // yt in [0,32)
  int m0 = yt * BM, n0 = xt * BN;

  int tid = threadIdx.x, wid = tid >> 6, lane = tid & 63;
  int srow = lane >> 3;
  int sgk = ((lane & 7) ^ srow) * 8;    // XOR-permuted global k-chunk
  int wm = (wid >> 1) * 128, wn = (wid & 1) * 64;
  int fm = lane & 15, fc = lane >> 4;

  // staging: wave w covers A rows [64w,64w+64) (8 sweeps), B rows [32w,32w+32)
  const _Float16* Ag = A  + (size_t)(m0 + 64 * wid + srow) * Kd + sgk;
  const _Float16* Bg = Bt + (size_t)(n0 + 32 * wid + srow) * Kd + sgk;

  f32x4 acc[8][4] = {};   // 128 VGPRs

  for (int kt = 0; kt < Kd / BK; ++kt) {
    if (kt) __syncthreads();
    int kk = kt * BK;
#pragma unroll
    for (int i = 0; i < 8; ++i)
      gl_lds16(Ag + kk + (size_t)(8 * i) * Kd, &As[(64 * wid + 8 * i) * BK]);
#pragma unroll
    for (int i = 0; i < 4; ++i)
      gl_lds16(Bg + kk + (size_t)(8 * i) * Kd, &Bs[(32 * wid + 8 * i) * BK]);
    __syncthreads();

#pragma unroll
    for (int ks = 0; ks < 2; ++ks) {
      h8v af[8], bfr[4];
#pragma unroll
      for (int i = 0; i < 8; ++i) {
        int row = wm + i * 16 + fm;
        af[i] = *(const h8v*)&As[row * BK + (((ks * 4 + fc) ^ (row & 7)) * 8)];
      }
#pragma unroll
      for (int j = 0; j < 4; ++j) {
        int row = wn + j * 16 + fm;
        bfr[j] = *(const h8v*)&Bs[row * BK + (((ks * 4 + fc) ^ (row & 7)) * 8)];
      }
#pragma unroll
      for (int i = 0; i < 8; ++i)
#pragma unroll
        for (int j = 0; j < 4; ++j)
          acc[i][j] = __builtin_amdgcn_mfma_f32_16x16x32_f16(af[i], bfr[j], acc[i][j], 0, 0, 0);
    }
  }

  int which = n0 >> 10, nc = n0 & 1023;  // BN=128 tile never crosses a 1024 col boundary
  _Float16* Cv = which == 0 ? C0 : (which == 1 ? C1 : C2);

  int rr = (lane >> 4) * 4, cc = lane & 15;
#pragma unroll
  for (int i = 0; i < 8; ++i)
#pragma unroll
    for (int j = 0; j < 4; ++j) {
      size_t base = (size_t)(m0 + wm + i * 16 + rr) * DM + (nc + wn + j * 16 + cc);
#pragma unroll
      for (int r = 0; r < 4; ++r)
        Cv[base + (size_t)r * DM] = (_Float16)acc[i][j][r];
    }
}

// ------- Wo GEMM: proven R6 128x128 structure (512 blocks, ~4 blocks/CU) ----
__global__ __launch_bounds__(256) void sda_gemm_wo_kernel(
    const _Float16* __restrict__ A, const _Float16* __restrict__ Bt,
    float* __restrict__ C) {
  constexpr int Kd = DM;
  constexpr int BM = 128, BN = 128, BK = 64;
  __shared__ __align__(16) _Float16 As[BM * BK];
  __shared__ __align__(16) _Float16 Bs[BN * BK];

  int blk = blockIdx.x;
  int xcd = blk & 7, slot = blk >> 3;   // 64 slots/XCD
  int xt = slot >> 3, ys = slot & 7;    // 8 x-tiles, x-major
  int yt = (xcd << 3) | ys;
  int m0 = yt * BM, n0 = xt * BN;

  int tid = threadIdx.x, wid = tid >> 6, lane = tid & 63;
  int srow = lane >> 3;
  int sgk = ((lane & 7) ^ (srow & 7)) * 8;
  int wm = (wid >> 1) * 64, wn = (wid & 1) * 64;
  int fm = lane & 15, fc = lane >> 4;

  f32x4 acc[4][4] = {};

  for (int kt = 0; kt < Kd / BK; ++kt) {
    if (kt) __syncthreads();
    int kk = kt * BK;
    int r0 = wid * 32;
#pragma unroll
    for (int i = 0; i < 4; ++i) {
      gl_lds16(A  + (size_t)(m0 + r0 + i * 8 + srow) * Kd + kk + sgk, &As[(r0 + i * 8) * BK]);
      gl_lds16(Bt + (size_t)(n0 + r0 + i * 8 + srow) * Kd + kk + sgk, &Bs[(r0 + i * 8) * BK]);
    }
    __syncthreads();

#pragma unroll
    for (int ks = 0; ks < 2; ++ks) {
      h8v af[4], bfr[4];
#pragma unroll
      for (int i = 0; i < 4; ++i) {
        int row = wm + i * 16 + fm;
        af[i] = *(const h8v*)&As[row * BK + (((ks * 4 + fc) ^ (row & 7)) * 8)];
      }
#pragma unroll
      for (int j = 0; j < 4; ++j) {
        int row = wn + j * 16 + fm;
        bfr[j] = *(const h8v*)&Bs[row * BK + (((ks * 4 + fc) ^ (row & 7)) * 8)];
      }
#pragma unroll
      for (int i = 0; i < 4; ++i)
#pragma unroll
        for (int j = 0; j < 4; ++j)
          acc[i][j] = __builtin_amdgcn_mfma_f32_16x16x32_f16(af[i], bfr[j], acc[i][j], 0, 0, 0);
    }
  }

  int rr = (lane >> 4) * 4, cc = lane & 15;
#pragma unroll
  for (int i = 0; i < 4; ++i)
#pragma unroll
    for (int j = 0; j < 4; ++j) {
      size_t base = (size_t)(m0 + wm + i * 16 + rr) * DM + (n0 + wn + j * 16 + cc);
#pragma unroll
      for (int r = 0; r < 4; ++r)
        C[base + (size_t)r * DM] = acc[i][j][r];
    }
}

// ---------------- BARRIER-FREE per-wave windowed attention ----------------
// Grid (S/64, B*H), 256 thr = 4 waves. Wave w owns q-rows [16w,16w+16) and
// needs ONLY K/V pos [s0+16w-8, s0+16w+15] (24 rows) -> per-wave LDS slices,
// ZERO __syncthreads (in-wave DS ordering via lgkmcnt only). Strides are
// odd-dword multiples (kw 144B, vt/wt 80B, sc 132B) -> <=2-way bank aliasing.
__global__ __launch_bounds__(256) void sda_attn_kernel(
    const _Float16* __restrict__ Q, const _Float16* __restrict__ K,
    const _Float16* __restrict__ V, _Float16* __restrict__ O) {
  constexpr int KS  = 72;  // kw row stride f16: 144B = 36 dw
  constexpr int VTS = 40;  // vt row stride f16: 80B = 20 dw
  constexpr int WS  = 40;  // wt row stride f16
  __shared__ __align__(16) _Float16 kw[4][32 * KS];   // 4.5 KB/wave
  __shared__ __align__(16) _Float16 vt[4][64 * VTS];  // 5 KB/wave [dim][key]
  __shared__ __align__(16) float    sc[4][16 * 33];   // 2.06 KB/wave
  __shared__ __align__(16) _Float16 wt[4][16 * WS];   // 1.25 KB/wave => 52.5 KB total

  int bh = blockIdx.y, b = bh >> 4, h = bh & 15;
  int s0 = blockIdx.x * 64;
  int tid = threadIdx.x, wid = tid >> 6, lane = tid & 63;
  size_t headoff = (size_t)b * S_LEN * DM + h * 64;

  _Float16* kwp = kw[wid];
  _Float16* vtp = vt[wid];
  float*    scp = sc[wid];
  _Float16* wtp = wt[wid];

  int p0 = s0 + wid * 16 - RAD;    // first key pos of this wave's 24-key band
  int fm = lane & 15, fkg = (lane >> 4) * 8;
  int rr = (lane >> 4) * 4, cc = lane & 15;

  // zero wt fully (1280 B = 80 x 16B) and vt key-cols 24..31 (0*NaN guard)
  {
    uint4 z = make_uint4(0, 0, 0, 0);
    ((uint4*)wtp)[lane] = z;
    if (lane < 16) ((uint4*)wtp)[64 + lane] = z;
    *(uint4*)&vtp[lane * VTS + 24] = z;
  }

  // stage K rows 0..23 row-major (24 x 8 chunks = 192 items, 3/lane)
#pragma unroll
  for (int i = 0; i < 3; ++i) {
    int item = i * 64 + lane;
    int row = item >> 3, ch = (item & 7) * 8;
    int pos = p0 + row;
    uint4 kv = make_uint4(0, 0, 0, 0);
    if (pos >= 0) kv = *(const uint4*)(K + headoff + (size_t)pos * DM + ch);
    *(uint4*)&kwp[row * KS + ch] = kv;
  }
  // stage V transposed: vt[dim][key]
#pragma unroll
  for (int i = 0; i < 3; ++i) {
    int item = i * 64 + lane;
    int row = item >> 3, chb = (item & 7) * 8;
    int pos = p0 + row;
    uint4 vv = make_uint4(0, 0, 0, 0);
    if (pos >= 0) vv = *(const uint4*)(V + headoff + (size_t)pos * DM + chb);
    union { uint4 v; _Float16 hh[8]; } u; u.v = vv;
#pragma unroll
    for (int d = 0; d < 8; ++d) vtp[(chb + d) * VTS + row] = u.hh[d];
  }

  // Q fragments straight from global (rows always valid)
  const _Float16* qrow = Q + headoff + (size_t)(s0 + wid * 16 + fm) * DM;
  h8v aq0 = *(const h8v*)(qrow + fkg);
  h8v aq1 = *(const h8v*)(qrow + 32 + fkg);

  // ---- QK^T: 2 local key-tiles x K=64 ----
  f32x4 accs[2] = {};
#pragma unroll
  for (int t = 0; t < 2; ++t) {
    h8v bk0 = *(const h8v*)&kwp[(t * 16 + fm) * KS + fkg];
    h8v bk1 = *(const h8v*)&kwp[(t * 16 + fm) * KS + 32 + fkg];
    accs[t] = __builtin_amdgcn_mfma_f32_16x16x32_f16(aq0, bk0, accs[t], 0, 0, 0);
    accs[t] = __builtin_amdgcn_mfma_f32_16x16x32_f16(aq1, bk1, accs[t], 0, 0, 0);
  }
#pragma unroll
  for (int t = 0; t < 2; ++t)
#pragma unroll
    for (int r = 0; r < 4; ++r)
      scp[(rr + r) * 33 + t * 16 + cc] = accs[t][r];

  // ---- softmax: lane r (0..15) owns q-row r; band cols r..r+8 (< 24) ----
  if (lane < 16) {
    int r = lane, s = s0 + wid * 16 + r;
    const float* my = &scp[r * 33 + r];
    float e[9], mx = -1e30f;
#pragma unroll
    for (int j = 0; j < 9; ++j) {
      float p = my[j] * INV2T;
      e[j] = (s - RAD + j >= 0) ? p : -1e30f;
      mx = fmaxf(mx, e[j]);
    }
    float se = 0.f;
#pragma unroll
    for (int j = 0; j < 9; ++j) { e[j] = __expf(e[j] - mx); se += e[j]; }
    float inv = 1.f / se;
#pragma unroll
    for (int j = 0; j < 9; ++j)
      wtp[r * WS + r + j] = (_Float16)(e[j] * inv);
  }

  // ---- PV: O(16x64) = wt(16x32) @ V(32x64); one K=32 MFMA per n-tile ----
  f32x4 acco[4] = {};
  h8v aw = *(const h8v*)&wtp[fm * WS + fkg];
#pragma unroll
  for (int t = 0; t < 4; ++t) {
    h8v bv = *(const h8v*)&vtp[(t * 16 + fm) * VTS + fkg];
    acco[t] = __builtin_amdgcn_mfma_f32_16x16x32_f16(aw, bv, acco[t], 0, 0, 0);
  }
#pragma unroll
  for (int t = 0; t < 4; ++t)
#pragma unroll
    for (int r = 0; r < 4; ++r)
      O[headoff + (size_t)(s0 + wid * 16 + rr + r) * DM + t * 16 + cc] =
          (_Float16)acco[t][r];
}

extern "C" void kernel_launch(void* const* d_in, const int* in_sizes, int n_in,
                              void* d_out, int out_size, void* d_ws, size_t ws_size,
                              hipStream_t stream) {
  (void)in_sizes; (void)n_in; (void)out_size; (void)ws_size;
  const float* x  = (const float*)d_in[0];
  const float* Wq = (const float*)d_in[1];
  const float* Wk = (const float*)d_in[2];
  const float* Wv = (const float*)d_in[3];
  const float* Wo = (const float*)d_in[4];

  char* ws = (char*)d_ws;
  const size_t MB = 1ull << 20;
  _Float16* xh    = (_Float16*)(ws + 0);        // 16 MB
  _Float16* WqkvT = (_Float16*)(ws + 16 * MB);  // 6 MB: Wq^T|Wk^T|Wv^T
  _Float16* WoT   = (_Float16*)(ws + 22 * MB);  // 2 MB
  _Float16* Qh    = (_Float16*)(ws + 24 * MB);  // 16 MB each
  _Float16* Kh    = (_Float16*)(ws + 40 * MB);
  _Float16* Vh    = (_Float16*)(ws + 56 * MB);
  _Float16* Ah    = (_Float16*)(ws + 72 * MB);  // total 88 MB

  sda_prep_kernel<<<dim3(32, 32, 8), dim3(32, 8), 0, stream>>>(
      x, xh, Wq, Wk, Wv, Wo,
      WqkvT, WqkvT + (size_t)DM * DM, WqkvT + 2ull * DM * DM, WoT);

  // QKV fused: M=8192, N=3072 -> 768 blocks (BM=256 x BN=128), 2 blocks/CU
  sda_gemm_qkv_fat<<<768, 256, 0, stream>>>(xh, WqkvT, Qh, Kh, Vh);
  sda_attn_kernel<<<dim3(64, 32), 256, 0, stream>>>(Qh, Kh, Vh, Ah);
  // Wo: 128x128 -> 512 blocks
  sda_gemm_wo_kernel<<<512, 256, 0, stream>>>(Ah, WoT, (float*)d_out);
}